// Round 8
// baseline (221.348 us; speedup 1.0000x reference)
//
#include <hip/hip_runtime.h>
#include <hip/hip_bf16.h>
#include <hip/hip_fp16.h>

// B=2048, D=256, K=256, NC=64, F=512.
// Q[b,c] = Qlin[b,c] + z^T M_c z, M_c = sum_k cq[c,k] Gamma_k.
// R8: atomic-free (qf/lin write per-split partials; final reduces),
// de-aliased ws (no memset dispatch), lin2 merged into qf (grid y==32).
// 5 dispatches: prep -> prep2 -> mc -> qf(+lin) -> final.

#define B_SZ 2048
#define D_SZ 256
#define K_SZ 256
#define NC_SZ 64
#define F_SZ 512
#define P_SZ 65536

typedef float  floatx4  __attribute__((ext_vector_type(4)));
typedef float  floatx16 __attribute__((ext_vector_type(16)));
typedef _Float16 h8 __attribute__((ext_vector_type(8)));
typedef __fp16  fp16x2 __attribute__((ext_vector_type(2)));
union H8U4 { uint4 u; h8 h; };

// ws layout (f32 offsets) — fully de-aliased (ws is 256 MB).
#define WS_WZT   0        // 256*64 f32
#define WS_WFT   16384    // 512*64 f32
#define WS_BEFF  49152    // 64
#define WS_CSQ   49216    // 64
#define WS_CQT   49280    // 256*64 f32
#define WS_CQH   65664    // f16[64*256] (8192 f32)
#define WS_LP    73856    // f32[4][2048*64]  lin partials (s=3 is dot)
#define WS_QP    598144   // f32[32][2048*64] qf partials
#define WS_MH    4792448  // f16[64*65536], XOR-swizzled within i-segments
#define WS_WALL  6889600  // 7 x 32KB pre-swizzled f16 LDS images
// end: 6946944 f32 = 27.8 MB (ws = 256 MB)

__device__ __forceinline__ unsigned pkrtz_u(float a, float b) {
    fp16x2 r = __builtin_amdgcn_cvt_pkrtz(a, b);
    return __builtin_bit_cast(unsigned, r);
}
__device__ __forceinline__ unsigned packh2(_Float16 a, _Float16 b) {
    union { _Float16 h[2]; unsigned u; } r; r.h[0] = a; r.h[1] = b; return r.u;
}
__device__ __forceinline__ unsigned packh(float a, float b) {
    return packh2((_Float16)a, (_Float16)b);
}

__device__ __forceinline__ void gload16(const void* g, void* l) {
    __builtin_amdgcn_global_load_lds(
        (const __attribute__((address_space(1))) unsigned*)g,
        (__attribute__((address_space(3))) unsigned*)l, 16, 0, 0);
}

// ---------------- prep: collapsed weights (f32), cqT, cqh, beff, csq --------
__global__ __launch_bounds__(256) void prep_kernel(
        const float* __restrict__ Wqz, const float* __restrict__ bqz,
        const float* __restrict__ Wqf, const float* __restrict__ bqf,
        const float* __restrict__ cq,  float* __restrict__ ws) {
    const int tid = threadIdx.x;
    const int w = tid >> 6, c = tid & 63;
    const int bid = blockIdx.x;

    if (bid >= 193) {  // cqh convert: no barrier on this path
        _Float16* cqh = (_Float16*)(ws + WS_CQH);
        const int idx = (bid - 193)*256 + tid;   // 0..2047, 8 f16 each
        const floatx4* sp = (const floatx4*)(cq + idx*8);
        floatx4 a = sp[0], b = sp[1];
        uint4 u = { pkrtz_u(a[0],a[1]), pkrtz_u(a[2],a[3]),
                    pkrtz_u(b[0],b[1]), pkrtz_u(b[2],b[3]) };
        *(uint4*)(cqh + idx*8) = u;
        return;
    }

    __shared__ float cqL[64*257];
    #pragma unroll
    for (int s = 0; s < 16; ++s) {
        const int e4 = s*256 + tid;
        const int row = e4 >> 6, col = (e4 & 63)*4;
        floatx4 v = *(const floatx4*)(cq + e4*4);
        #pragma unroll
        for (int u = 0; u < 4; ++u) cqL[row*257 + col + u] = v[u];
    }
    __syncthreads();

    if (bid < 64) {
        const int i = bid*4 + w;
        float acc = 0.f;
        #pragma unroll 4
        for (int k = 0; k < K_SZ; ++k)
            acc = fmaf(cqL[c*257 + k], Wqz[k*D_SZ + i], acc);
        ws[WS_WZT + i*64 + c] = acc;
        ws[WS_CQT + i*64 + c] = cqL[c*257 + i];
    } else if (bid < 192) {
        const int j = (bid - 64)*4 + w;
        float acc = 0.f;
        #pragma unroll 4
        for (int k = 0; k < K_SZ; ++k)
            acc = fmaf(cqL[c*257 + k], Wqf[k*F_SZ + j], acc);
        ws[WS_WFT + j*64 + c] = acc;
    } else {
        if (w == 0) {
            float acc = 0.f;
            for (int k = 0; k < K_SZ; ++k)
                acc = fmaf(cqL[c*257 + k], bqz[k] + bqf[k], acc);
            ws[WS_BEFF + c] = acc;
        } else if (w == 1) {
            float acc = 0.f;
            for (int i = 0; i < D_SZ; ++i) {
                const float v = cqL[c*257 + i];
                acc = fmaf(v, v, acc);
            }
            ws[WS_CSQ + c] = acc;
        }
    }
}

// ---------------- prep2: pack 7 wAll images (pre-swizzled) ------------------
// slices: 0=wz_hi | 1=wf0_hi 2=wf0_lo | 3=wf1_hi 4=wf1_lo | 5=cq_hi 6=cq_lo
__global__ __launch_bounds__(256) void prep2_kernel(float* __restrict__ ws) {
    const int gi = blockIdx.x*256 + threadIdx.x;   // 0..14335
    const int s  = gi >> 11, e = gi & 2047;
    const int cr = e >> 5,  u = e & 31;
    const float* __restrict__ src =
        (s == 0) ? ws + WS_WZT :
        (s <= 2) ? ws + WS_WFT :
        (s <= 4) ? ws + WS_WFT + 16384 : ws + WS_CQT;
    const bool lo = (s == 2) || (s == 4) || (s == 6);
    float v[8];
    #pragma unroll
    for (int off = 0; off < 8; ++off)
        v[off] = src[(u*8 + off)*64 + cr];
    uint4 o;
    if (!lo) {
        o.x = packh(v[0], v[1]); o.y = packh(v[2], v[3]);
        o.z = packh(v[4], v[5]); o.w = packh(v[6], v[7]);
    } else {
        float l[8];
        #pragma unroll
        for (int off = 0; off < 8; ++off) {
            const _Float16 h = (_Float16)v[off];
            l[off] = (v[off] - (float)h) * 1024.f;
        }
        o.x = pkrtz_u(l[0], l[1]); o.y = pkrtz_u(l[2], l[3]);
        o.z = pkrtz_u(l[4], l[5]); o.w = pkrtz_u(l[6], l[7]);
    }
    char* wall = (char*)(ws + WS_WALL);
    *(uint4*)(wall + s*32768 + cr*512 + ((u ^ (cr & 31)) << 4)) = o;
}

// ---------------- mc: M[c,p] = sum_k cq[c,k] Gamma[k,p] via MFMA, no LDS ----
__global__ __launch_bounds__(256, 4) void mc_kernel(
        const float* __restrict__ gamma, const _Float16* __restrict__ cqh,
        _Float16* __restrict__ mh) {
    const int tid = threadIdx.x;
    const int w = tid >> 6, lane = tid & 63;
    const int ln = lane & 31, half = lane >> 5;
    const int mt = w >> 1, ns = w & 1;
    const int p0 = blockIdx.x * 64;
    const int iseg = p0 >> 8, j0 = p0 & 255;

    floatx16 acc;
    #pragma unroll
    for (int r = 0; r < 16; ++r) acc[r] = 0.f;

    const int arow = mt*32 + ln;
    const float* __restrict__ gbase = gamma + (size_t)(half*8)*P_SZ + p0 + ns*32 + ln;

    #pragma unroll 2
    for (int kc = 0; kc < 16; ++kc) {
        float g[8];
        #pragma unroll
        for (int kk = 0; kk < 8; ++kk)
            g[kk] = gbase[(size_t)(kc*16 + kk)*P_SZ];     // coalesced 128B/row
        H8U4 a; a.u = *(const uint4*)(cqh + arow*256 + kc*16 + half*8);
        H8U4 b;
        b.u.x = pkrtz_u(g[0], g[1]);
        b.u.y = pkrtz_u(g[2], g[3]);
        b.u.z = pkrtz_u(g[4], g[5]);
        b.u.w = pkrtz_u(g[6], g[7]);
        acc = __builtin_amdgcn_mfma_f32_32x32x16_f16(a.h, b.h, acc, 0, 0, 0);
    }
    // D: col=lane&31 (p), row=(r&3)+8*(r>>2)+4*half (c)  [m74/m101]
    #pragma unroll
    for (int r = 0; r < 16; ++r) {
        const int cc = mt*32 + (r&3) + 8*(r>>2) + 4*half;
        const int j  = j0 + ns*32 + ln;
        const int jc = j >> 3, off = j & 7;
        mh[(size_t)cc*P_SZ + iseg*256 + ((jc ^ (cc&31))*8 + off)] = (_Float16)acc[r];
    }
}

// ---------------- qf: quadratic partials (y<32) + linear partials (y==32) ---
// y<32:  Q2 partial over i-group ig -> qp[ig][b*64+c] (plain stores).
// y==32: 4 slices (z·wz | feat·wf Dekker x2 | z·cq Dekker) -> lp[s][b*64+c].
__global__ __launch_bounds__(512, 1) void qf_kernel(
        const float* __restrict__ z, const float* __restrict__ feat,
        const _Float16* __restrict__ mh, const float* __restrict__ wall_f,
        float* __restrict__ qp, float* __restrict__ lp) {
    __shared__ __align__(16) char bt[2][64 * 512];
    const int tid = threadIdx.x;
    const int w = tid >> 6, lane = tid & 63;
    const int ln = lane & 31, half = lane >> 5;
    const int b0 = blockIdx.x * 256;
    const int bb = b0 + w*32 + ln;

    if (blockIdx.y == 32) {
        // ---- linear mode ----
        const char* wall = (const char*)wall_f;
        for (int s = 0; s < 4; ++s) {
            const int s_hi = (s == 0) ? 0 : (s == 1) ? 1 : (s == 2) ? 3 : 5;
            #pragma unroll
            for (int e0 = 0; e0 < 4; ++e0) {
                const int e = e0*512 + tid;
                gload16(wall + s_hi*32768 + e*16, bt[0] + e*16);
            }
            if (s > 0) {
                #pragma unroll
                for (int e0 = 0; e0 < 4; ++e0) {
                    const int e = e0*512 + tid;
                    gload16(wall + (s_hi + 1)*32768 + e*16, bt[1] + e*16);
                }
            }
            const float* __restrict__ arow =
                (s == 0 || s == 3) ? z + bb*D_SZ
                                   : feat + bb*F_SZ + (s == 2 ? 256 : 0);
            __syncthreads();

            floatx16 hh0, hh1, lh0, lh1, hl0, hl1;
            #pragma unroll
            for (int r = 0; r < 16; ++r) {
                hh0[r] = 0.f; hh1[r] = 0.f; lh0[r] = 0.f;
                lh1[r] = 0.f; hl0[r] = 0.f; hl1[r] = 0.f;
            }
            #pragma unroll
            for (int ch = 0; ch < 16; ++ch) {
                const floatx4* ap = (const floatx4*)(arow + ch*16 + half*8);
                floatx4 a4 = ap[0], b4 = ap[1];
                float vv[8];
                #pragma unroll
                for (int t = 0; t < 4; ++t) { vv[t] = a4[t]; vv[4+t] = b4[t]; }
                _Float16 hc[8];
                #pragma unroll
                for (int j = 0; j < 8; ++j) hc[j] = (_Float16)vv[j];
                H8U4 ah;
                ah.u.x = packh2(hc[0], hc[1]); ah.u.y = packh2(hc[2], hc[3]);
                ah.u.z = packh2(hc[4], hc[5]); ah.u.w = packh2(hc[6], hc[7]);

                const int pc = ((ch*2 + half) ^ ln) * 16;
                H8U4 f0, f1;
                f0.u = *(const uint4*)(bt[0] + ln*512 + pc);
                f1.u = *(const uint4*)(bt[0] + (32 + ln)*512 + pc);
                hh0 = __builtin_amdgcn_mfma_f32_32x32x16_f16(ah.h, f0.h, hh0, 0, 0, 0);
                hh1 = __builtin_amdgcn_mfma_f32_32x32x16_f16(ah.h, f1.h, hh1, 0, 0, 0);
                if (s > 0) {
                    float l[8];
                    #pragma unroll
                    for (int j = 0; j < 8; ++j) l[j] = (vv[j] - (float)hc[j]) * 1024.f;
                    H8U4 al;
                    al.u.x = pkrtz_u(l[0], l[1]); al.u.y = pkrtz_u(l[2], l[3]);
                    al.u.z = pkrtz_u(l[4], l[5]); al.u.w = pkrtz_u(l[6], l[7]);
                    H8U4 g0, g1;
                    g0.u = *(const uint4*)(bt[1] + ln*512 + pc);
                    g1.u = *(const uint4*)(bt[1] + (32 + ln)*512 + pc);
                    lh0 = __builtin_amdgcn_mfma_f32_32x32x16_f16(al.h, f0.h, lh0, 0, 0, 0);
                    lh1 = __builtin_amdgcn_mfma_f32_32x32x16_f16(al.h, f1.h, lh1, 0, 0, 0);
                    hl0 = __builtin_amdgcn_mfma_f32_32x32x16_f16(ah.h, g0.h, hl0, 0, 0, 0);
                    hl1 = __builtin_amdgcn_mfma_f32_32x32x16_f16(ah.h, g1.h, hl1, 0, 0, 0);
                }
            }
            const float is = 1.0f / 1024.0f;
            float* __restrict__ lps = lp + s*(B_SZ*NC_SZ);
            #pragma unroll
            for (int r = 0; r < 16; ++r) {
                const int row  = (r&3) + 8*(r>>2) + 4*half;
                const int brow = b0 + w*32 + row;
                float v0 = hh0[r], v1 = hh1[r];
                if (s > 0) { v0 += (lh0[r] + hl0[r])*is; v1 += (lh1[r] + hl1[r])*is; }
                lps[brow*NC_SZ + ln]      = v0;
                lps[brow*NC_SZ + 32 + ln] = v1;
            }
            __syncthreads();
        }
        return;
    }

    // ---- quadratic mode ----
    const int ig = blockIdx.y;
    uint4 zjh[16];
    #pragma unroll
    for (int ch = 0; ch < 16; ++ch) {
        const floatx4* zp = (const floatx4*)(z + bb*D_SZ + ch*16 + half*8);
        floatx4 a = zp[0], b = zp[1];
        zjh[ch].x = pkrtz_u(a[0], a[1]);
        zjh[ch].y = pkrtz_u(a[2], a[3]);
        zjh[ch].z = pkrtz_u(b[0], b[1]);
        zjh[ch].w = pkrtz_u(b[2], b[3]);
    }
    float ziv[8];
    {
        const floatx4* zp = (const floatx4*)(z + bb*D_SZ + ig*8);
        floatx4 a = zp[0], b = zp[1];
        #pragma unroll
        for (int t = 0; t < 4; ++t) { ziv[t] = a[t]; ziv[4+t] = b[t]; }
    }

    floatx16 acc0, acc1;
    #pragma unroll
    for (int r = 0; r < 16; ++r) { acc0[r] = 0.f; acc1[r] = 0.f; }

    #define STAGE(i, sel)                                                     \
        _Pragma("unroll")                                                     \
        for (int s = 0; s < 4; ++s) {                                         \
            const int e = s*512 + tid;                                        \
            gload16((const char*)mh +                                         \
                    ((size_t)(e >> 5)*P_SZ + (size_t)(i)*256)*2 + (e & 31)*16,\
                    bt[sel] + e*16);                                          \
        }

    STAGE(ig*8, 0);
    for (int il = 0; il < 8; ++il) {
        __syncthreads();
        if (il < 7) { STAGE(ig*8 + il + 1, (il + 1) & 1); }

        const float zi = ziv[il];
        const unsigned zu = pkrtz_u(zi, zi);
        H8U4 zb; zb.u.x = zu; zb.u.y = zu; zb.u.z = zu; zb.u.w = zu;
        const char* btc = bt[il & 1];
        #pragma unroll
        for (int ch = 0; ch < 16; ++ch) {
            H8U4 aj; aj.u = zjh[ch];
            h8 af = aj.h * zb.h;
            const int pc = ((ch*2 + half) ^ ln) * 16;
            H8U4 f0, f1;
            f0.u = *(const uint4*)(btc + ln*512 + pc);
            f1.u = *(const uint4*)(btc + (32 + ln)*512 + pc);
            acc0 = __builtin_amdgcn_mfma_f32_32x32x16_f16(af, f0.h, acc0, 0, 0, 0);
            acc1 = __builtin_amdgcn_mfma_f32_32x32x16_f16(af, f1.h, acc1, 0, 0, 0);
        }
    }
    #undef STAGE

    float* __restrict__ qps = qp + ig*(B_SZ*NC_SZ);
    #pragma unroll
    for (int r = 0; r < 16; ++r) {
        const int row  = (r&3) + 8*(r>>2) + 4*half;
        const int brow = b0 + w*32 + row;
        qps[brow*NC_SZ + ln]      = acc0[r];
        qps[brow*NC_SZ + 32 + ln] = acc1[r];
    }
}

// ---------------- final: reduce partials + f64 score + softmax/argmax -------
__global__ __launch_bounds__(256) void final_kernel(
        const float* __restrict__ z, const float* __restrict__ ws,
        float* __restrict__ out) {
    const int w = threadIdx.x >> 6, c = threadIdx.x & 63;
    const int b = blockIdx.x*4 + w;
    const int base = b*NC_SZ + c;

    // r2 = |z_b|^2 : lane c owns 4 elements, butterfly reduce
    const floatx4 zv = *(const floatx4*)(z + b*D_SZ + c*4);
    float r2 = zv[0]*zv[0] + zv[1]*zv[1] + zv[2]*zv[2] + zv[3]*zv[3];
    #pragma unroll
    for (int off = 32; off > 0; off >>= 1)
        r2 += __shfl_xor(r2, off, 64);

    const float* __restrict__ qp = ws + WS_QP;
    const float* __restrict__ lp = ws + WS_LP;
    float qsum = ws[WS_BEFF + c];
    #pragma unroll
    for (int g = 0; g < 32; ++g) qsum += qp[g*(B_SZ*NC_SZ) + base];
    #pragma unroll
    for (int s = 0; s < 3; ++s)  qsum += lp[s*(B_SZ*NC_SZ) + base];
    const float dotv = lp[3*(B_SZ*NC_SZ) + base];

    const float Q   = qsum;
    const float csq = ws[WS_CSQ + c];
    const float dsq = fmaf(-2.f, dotv, r2) + csq;

    const double r2d = (double)r2, csqd = (double)csq, dsqd = (double)dsq;
    const double denom = (1.0 - r2d) * (1.0 - csqd);
    double arg = 1.0 + 2.0 * dsqd / (denom + 0.001);
    if (arg < 1.001) arg = 1.001;
    const double dist = acosh(arg);
    double tmp = 1.0 - r2d; if (tmp < 0.001) tmp = 0.001;
    double tau = 8.0 * tmp;  // sqrt(256)*0.5
    if (tau < 0.01) tau = 0.01;
    double r2c = r2d; if (r2c > 0.999) r2c = 0.999;
    const double lam = 2.0 / (1.0 - r2c + 0.001);
    const double score = -dist / tau + 0.1 * ((double)Q / lam) / tau;

    double m = score;
    #pragma unroll
    for (int off = 32; off > 0; off >>= 1) {
        double o = __shfl_xor(m, off, 64);
        m = fmax(m, o);
    }
    const double e = exp(score - m);
    double s = e;
    #pragma unroll
    for (int off = 32; off > 0; off >>= 1) s += __shfl_xor(s, off, 64);
    out[base] = (float)(e / s);

    double bsc = score; int bix = c;
    #pragma unroll
    for (int off = 32; off > 0; off >>= 1) {
        double osc = __shfl_xor(bsc, off, 64);
        int    oix = __shfl_xor(bix, off, 64);
        if (osc > bsc || (osc == bsc && oix < bix)) { bsc = osc; bix = oix; }
    }
    if (c == 0) out[B_SZ*NC_SZ + b] = (float)bix;
}

extern "C" void kernel_launch(void* const* d_in, const int* in_sizes, int n_in,
                              void* d_out, int out_size, void* d_ws, size_t ws_size,
                              hipStream_t stream) {
    const float* z    = (const float*)d_in[0];
    const float* feat = (const float*)d_in[1];
    const float* Wqz  = (const float*)d_in[2];
    const float* bqz  = (const float*)d_in[3];
    const float* Wqf  = (const float*)d_in[4];
    const float* bqf  = (const float*)d_in[5];
    const float* gamma= (const float*)d_in[6];
    const float* cq   = (const float*)d_in[7];
    float* out = (float*)d_out;
    float* ws  = (float*)d_ws;
    _Float16* cqh = (_Float16*)(ws + WS_CQH);
    _Float16* mh  = (_Float16*)(ws + WS_MH);

    prep_kernel<<<201, 256, 0, stream>>>(Wqz, bqz, Wqf, bqf, cq, ws);
    prep2_kernel<<<56, 256, 0, stream>>>(ws);
    mc_kernel<<<1024, 256, 0, stream>>>(gamma, cqh, mh);
    qf_kernel<<<dim3(8, 33), 512, 0, stream>>>(z, feat, mh, ws + WS_WALL,
                                               ws + WS_QP, ws + WS_LP);
    final_kernel<<<512, 256, 0, stream>>>(z, ws, out);
}